// Round 10
// baseline (481.301 us; speedup 1.0000x reference)
//
#include <hip/hip_runtime.h>

typedef __attribute__((ext_vector_type(4))) float f32x4;
typedef __attribute__((ext_vector_type(8))) _Float16 f16x8;
typedef __attribute__((ext_vector_type(4))) unsigned short u16x4;
typedef __attribute__((ext_vector_type(8))) unsigned short u16x8;

#define NB 4096
#define NS 6
#define NC 2048
#define MTOT (NB * NS)   // 24576

static __device__ __forceinline__ unsigned short f2h_bits(float f) {
  _Float16 h = (_Float16)f;
  unsigned short b;
  __builtin_memcpy(&b, &h, 2);
  return b;
}
static __device__ __forceinline__ float h2f(unsigned short b) {
  _Float16 h;
  __builtin_memcpy(&h, &b, 2);
  return (float)h;
}

// ---------------- prep: fp32 -> fp16 ----------------
__global__ void conv_f16_kernel(const float* __restrict__ in,
                                unsigned short* __restrict__ out, int n4) {
  int i = blockIdx.x * blockDim.x + threadIdx.x;
  const int stride = gridDim.x * blockDim.x;
  for (; i < n4; i += stride) {
    f32x4 v = reinterpret_cast<const f32x4*>(in)[i];
    u16x4 o;
#pragma unroll
    for (int j = 0; j < 4; ++j) o[j] = f2h_bits(v[j]);
    reinterpret_cast<u16x4*>(out)[i] = o;
  }
}

// ------------- prep: [Wq;Wk] stacked -> fp16, 512 x 2048 -------------
__global__ void prep_wqk_kernel(const float* __restrict__ Wq,
                                const float* __restrict__ Wk,
                                unsigned short* __restrict__ w) {
  int i = blockIdx.x * blockDim.x + threadIdx.x;
  const int stride = gridDim.x * blockDim.x;
  for (; i < 262144; i += stride) {
    const int row = i >> 9;
    const int col4 = i & 511;
    const float* src = (row < 256) ? (Wq + (size_t)row * NC)
                                   : (Wk + (size_t)(row - 256) * NC);
    f32x4 v = reinterpret_cast<const f32x4*>(src)[col4];
    u16x4 o;
#pragma unroll
    for (int j = 0; j < 4; ++j) o[j] = f2h_bits(v[j]);
    reinterpret_cast<u16x4*>(w)[i] = o;
  }
}

// ---------------- 128x128 GEMM, BK=32, dbuf, 4 blocks/CU ----------------
// C[M,N] = A[M,2048] * B[N,2048]^T ; A/B fp16, C fp32.
// 4 waves (2x2), per-wave 64x64 out -> acc 64 VGPR -> ~120 total ->
// 4 waves/SIMD; LDS 2 x (A 8KB + B 8KB) = 32KB -> 4 blocks/CU (VGPR-capped).
// Per K-tile: {vmcnt(0); barrier; stage(tile+1); ds_read 8 frags; 16 MFMA}.
// vmcnt(0) drains only this wave's 4 stage ops (issued one full tile earlier);
// barrier then guarantees all waves' stages landed. Single barrier per tile.
// Cross-block occupancy (4/CU) covers latency/barrier stalls (m114 mechanism).
// Subtile = 1KB = [16 rows][32 k] fp16 with q^(r>>2) bank spread on both sides.

#define FENCE() asm volatile("" ::: "memory")
#define VM0BAR() do { FENCE(); asm volatile("s_waitcnt vmcnt(0)" ::: "memory"); \
                      __builtin_amdgcn_s_barrier(); FENCE(); } while (0)

__device__ __forceinline__ void stage128(const unsigned short* gA,
                                         const unsigned short* gB, int m0, int n0,
                                         int k0, char* buf, int wid, int lane) {
  // source-lane permutation matching the LDS read swizzle
  const int sl = lane ^ ((lane >> 4) & 1) ^ (((lane >> 5) & 1) << 1);
  const int rr = sl >> 2;
  const int kc = (sl & 3) * 8;
#pragma unroll
  for (int i = 0; i < 2; ++i) {
    const int c = wid * 2 + i;
    const unsigned short* sA = gA + (size_t)(m0 + c * 16 + rr) * 2048 + (k0 + kc);
    __builtin_amdgcn_global_load_lds(
        (__attribute__((address_space(1))) void*)sA,
        (__attribute__((address_space(3))) void*)(buf + c * 1024), 16, 0, 0);
    const unsigned short* sB = gB + (size_t)(n0 + c * 16 + rr) * 2048 + (k0 + kc);
    __builtin_amdgcn_global_load_lds(
        (__attribute__((address_space(1))) void*)sB,
        (__attribute__((address_space(3))) void*)(buf + 8192 + c * 1024), 16, 0, 0);
  }
}

template <int N, bool EPI, bool NFAST>
__global__ void __launch_bounds__(256, 4)
gemm128(const unsigned short* __restrict__ A, const unsigned short* __restrict__ B,
        float* __restrict__ C, const float* __restrict__ resid,
        const float* __restrict__ gam) {
  constexpr int NT = 64;               // K-tiles (BK=32, K=2048)
  constexpr int MT = MTOT / 128;       // 192
  constexpr int NXT = N / 128;
  constexpr int NWG = MT * NXT;        // %8==0 for both call sites
  constexpr int CPX = NWG / 8;
  __shared__ char lds[32768];

  const int bid = blockIdx.x;
  const int wg = (bid & 7) * CPX + (bid >> 3);   // XCD swizzle
  const int bx = NFAST ? (wg % NXT) : (wg / MT);
  const int by = NFAST ? (wg / NXT) : (wg % MT);
  const int m0 = by * 128, n0 = bx * 128;

  const int t = threadIdx.x;
  const int lane = t & 63;
  const int wid = t >> 6;              // 0..3
  const int wr = wid >> 1, wc = wid & 1;
  const int laneOff = (lane & 15) * 64 + (lane >> 4) * 16;
  const int swzOff = laneOff ^ (((laneOff >> 9) & 1) << 5) ^ (((laneOff >> 8) & 1) << 4);
  const int aBase = wr * 4096 + swzOff;          // A rows wr*64..wr*64+63
  const int bBase = 8192 + wc * 4096 + swzOff;   // B rows wc*64..wc*64+63

  f32x4 acc[4][4] = {};

#define STAGE(TT) stage128(A, B, m0, n0, (TT) * 32, lds + ((TT) & 1) * 16384, wid, lane)

  STAGE(0);

  for (int tau = 0; tau < NT; ++tau) {
    VM0BAR();                          // own stage(tau) drained; barrier -> all landed
    if (tau + 1 < NT) STAGE(tau + 1);  // writes the other buffer (safe post-barrier)
    const char* bufc = lds + (tau & 1) * 16384;
    f16x8 Af[4], Bf[4];
#pragma unroll
    for (int m = 0; m < 4; ++m)
      Af[m] = *reinterpret_cast<const f16x8*>(bufc + aBase + m * 1024);
#pragma unroll
    for (int n = 0; n < 4; ++n)
      Bf[n] = *reinterpret_cast<const f16x8*>(bufc + bBase + n * 1024);
    __builtin_amdgcn_s_setprio(1);
#pragma unroll
    for (int m = 0; m < 4; ++m)
#pragma unroll
      for (int n = 0; n < 4; ++n)
        acc[m][n] = __builtin_amdgcn_mfma_f32_16x16x32_f16(Af[m], Bf[n], acc[m][n], 0, 0, 0);
    __builtin_amdgcn_s_setprio(0);
  }
#undef STAGE

  // epilogue: C/D layout col = lane&15, row = (lane>>4)*4 + j
  const float g = EPI ? gam[0] : 0.f;
#pragma unroll
  for (int m = 0; m < 4; ++m)
#pragma unroll
    for (int n = 0; n < 4; ++n)
#pragma unroll
      for (int j = 0; j < 4; ++j) {
        const int r = m0 + wr * 64 + m * 16 + (lane >> 4) * 4 + j;
        const int c = n0 + wc * 64 + n * 16 + (lane & 15);
        const size_t idx = (size_t)r * (size_t)N + (size_t)c;
        float v = acc[m][n][j];
        if (EPI) v = g * v + resid[idx];
        C[idx] = v;
      }
}

// ---------------- per-batch: energy -> softmax -> attn out + y = attn@x ----------------
__global__ void __launch_bounds__(256)
attn_fuse(const float* __restrict__ QK,          // [MTOT, 512] cols 0..255=q, 256..511=k
          const unsigned short* __restrict__ xh, // [MTOT, 2048] fp16
          float* __restrict__ attn_out,          // [NB, 36]
          unsigned short* __restrict__ y)        // [MTOT, 2048] fp16
{
  __shared__ float qk[NS * 512];
  __shared__ float eng[36];
  __shared__ float att[36];
  const int b = blockIdx.x;
  const int t = threadIdx.x;
  {
    const f32x4* src = reinterpret_cast<const f32x4*>(QK + (size_t)b * (NS * 512));
    f32x4* dst = reinterpret_cast<f32x4*>(qk);
    for (int i = t; i < (NS * 512) / 4; i += 256) dst[i] = src[i];
  }
  __syncthreads();
  if (t < 144) {
    const int s = t / 24;
    const int rem = t - s * 24;
    const int u = rem >> 2;
    const int sub = rem & 3;
    const float* qr = qk + s * 512;
    const float* kr = qk + u * 512 + 256;
    float sum = 0.f;
    const int d0 = sub * 64;
#pragma unroll 4
    for (int d = 0; d < 64; ++d) sum += qr[d0 + d] * kr[d0 + d];
    sum += __shfl_xor(sum, 1);
    sum += __shfl_xor(sum, 2);
    if (sub == 0) eng[s * 6 + u] = sum;
  }
  __syncthreads();
  if (t < 6) {
    float e[6];
#pragma unroll
    for (int u = 0; u < 6; ++u) e[u] = eng[t * 6 + u];
    float mx = e[0];
#pragma unroll
    for (int u = 1; u < 6; ++u) mx = fmaxf(mx, e[u]);
    float p[6];
    float sm = 0.f;
#pragma unroll
    for (int u = 0; u < 6; ++u) { p[u] = expf(e[u] - mx); sm += p[u]; }
    const float inv = 1.0f / sm;
#pragma unroll
    for (int u = 0; u < 6; ++u) {
      const float a = p[u] * inv;
      att[t * 6 + u] = a;
      attn_out[(size_t)b * 36 + t * 6 + u] = a;
    }
  }
  __syncthreads();
  const unsigned short* xb = xh + (size_t)b * (NS * NC);
  unsigned short* yb = y + (size_t)b * (NS * NC);
  const int c0 = t * 8;
  f32x4 xv[12];
#pragma unroll
  for (int u = 0; u < 6; ++u) {
    u16x8 v = *reinterpret_cast<const u16x8*>(xb + u * NC + c0);
#pragma unroll
    for (int j = 0; j < 4; ++j) {
      xv[2 * u][j] = h2f(v[j]);
      xv[2 * u + 1][j] = h2f(v[4 + j]);
    }
  }
#pragma unroll
  for (int s = 0; s < 6; ++s) {
    f32x4 a0 = 0.f, a1 = 0.f;
#pragma unroll
    for (int u = 0; u < 6; ++u) {
      const float w = att[s * 6 + u];
      a0 += w * xv[2 * u];
      a1 += w * xv[2 * u + 1];
    }
    u16x8 o;
#pragma unroll
    for (int j = 0; j < 4; ++j) { o[j] = f2h_bits(a0[j]); o[4 + j] = f2h_bits(a1[j]); }
    *reinterpret_cast<u16x8*>(yb + s * NC + c0) = o;
  }
}

extern "C" void kernel_launch(void* const* d_in, const int* in_sizes, int n_in,
                              void* d_out, int out_size, void* d_ws, size_t ws_size,
                              hipStream_t stream) {
  (void)in_sizes; (void)n_in; (void)out_size; (void)ws_size;
  const float* x   = (const float*)d_in[0];
  const float* Wq  = (const float*)d_in[1];
  const float* Wk  = (const float*)d_in[2];
  const float* Wv  = (const float*)d_in[3];
  const float* gam = (const float*)d_in[4];
  float* out = (float*)d_out;
  float* attn_out = out + (size_t)MTOT * NC;

  char* ws = (char*)d_ws;
  unsigned short* xh  = (unsigned short*)(ws);                    // 100663296 B
  unsigned short* yb  = (unsigned short*)(ws + 100663296ull);     // 100663296 B (y)
  unsigned short* wqk = (unsigned short*)(ws + 201326592ull);     // 2097152 B
  unsigned short* wvh = (unsigned short*)(ws + 203423744ull);     // 8388608 B
  float*          qkb = (float*)(ws + 211812352ull);              // 50331648 B

  conv_f16_kernel<<<2048, 256, 0, stream>>>(x, xh, MTOT * NC / 4);
  prep_wqk_kernel<<<256, 256, 0, stream>>>(Wq, Wk, wqk);
  conv_f16_kernel<<<512, 256, 0, stream>>>(Wv, wvh, NC * NC / 4);

  // QK = x @ [Wq;Wk]^T, single-pass fp16 (768 blocks -> full machine fill)
  gemm128<512, false, false><<<768, 256, 0, stream>>>(
      xh, wqk, qkb, nullptr, nullptr);

  // energies + softmax + attention output + y = attn @ x
  attn_fuse<<<NB, 256, 0, stream>>>(qkb, xh, attn_out, yb);

  // out = gamma * (y @ Wv^T) + x    (n-fast block order for y/Wv L2 reuse)
  gemm128<2048, true, true><<<3072, 256, 0, stream>>>(
      yb, wvh, out, x, gam);
}

// Round 12
// 407.880 us; speedup vs baseline: 1.1800x; 1.1800x over previous
//
#include <hip/hip_runtime.h>

typedef __attribute__((ext_vector_type(4))) float f32x4;
typedef __attribute__((ext_vector_type(8))) _Float16 f16x8;
typedef __attribute__((ext_vector_type(4))) unsigned short u16x4;
typedef __attribute__((ext_vector_type(8))) unsigned short u16x8;

#define NB 4096
#define NS 6
#define NC 2048
#define MTOT (NB * NS)   // 24576

static __device__ __forceinline__ unsigned short f2h_bits(float f) {
  _Float16 h = (_Float16)f;
  unsigned short b;
  __builtin_memcpy(&b, &h, 2);
  return b;
}
static __device__ __forceinline__ float h2f(unsigned short b) {
  _Float16 h;
  __builtin_memcpy(&h, &b, 2);
  return (float)h;
}

// ---------------- fused prep: x->fp16, [Wq;Wk]->fp16, Wv->fp16 ----------------
#define NX4 12582912   // MTOT*NC/4
#define NW4 262144     // 512*2048/4
#define NV4 1048576    // 2048*2048/4
__global__ void prep_all(const float* __restrict__ x, const float* __restrict__ Wq,
                         const float* __restrict__ Wk, const float* __restrict__ Wv,
                         unsigned short* __restrict__ xh, unsigned short* __restrict__ wqk,
                         unsigned short* __restrict__ wvh) {
  long i = blockIdx.x * blockDim.x + threadIdx.x;
  const long stride = (long)gridDim.x * blockDim.x;
  for (; i < NX4 + NW4 + NV4; i += stride) {
    f32x4 v;
    unsigned short* dst;
    long di;
    if (i < NX4) {
      v = reinterpret_cast<const f32x4*>(x)[i];
      dst = xh; di = i;
    } else if (i < NX4 + NW4) {
      const long j = i - NX4;
      const int row = (int)(j >> 9);
      const int col4 = (int)(j & 511);
      const float* src = (row < 256) ? (Wq + (size_t)row * NC)
                                     : (Wk + (size_t)(row - 256) * NC);
      v = reinterpret_cast<const f32x4*>(src)[col4];
      dst = wqk; di = j;
    } else {
      const long j = i - NX4 - NW4;
      v = reinterpret_cast<const f32x4*>(Wv)[j];
      dst = wvh; di = j;
    }
    u16x4 o;
#pragma unroll
    for (int j = 0; j < 4; ++j) o[j] = f2h_bits(v[j]);
    reinterpret_cast<u16x4*>(dst)[di] = o;
  }
}

// ---------------- 256x256 GEMM, BK=64, merged tile (4 alignment pts/tile) ----------------
// C[M,N] = A[M,2048] * B[N,2048]^T ; A/B fp16, C fp32.
// LDS: 2 buf x (A 32KB + B 32KB) = 128KB. Subtile = 1KB = [16 rows][32 k] fp16.
// Staging ledger IDENTICAL to verified rounds 4-9: tile tau stages A(tau+1),
// B(tau+2); vmcnt(4) once per tile keeps exactly B(tau+2) in flight; WRAPT past
// NT keeps the count exact at the tail. HAZARD RULE (round-11 fix): every
// wave's reads of buf tau are ISSUED before a barrier, and the overwriting
// STAGE_B(tau+2) is issued only AFTER that barrier (VMEM write latency >>
// queued-ds_read service time) -- the discipline rounds 4-9 validated.

#define FENCE() asm volatile("" ::: "memory")
#define BAR() do { FENCE(); __builtin_amdgcn_s_barrier(); FENCE(); } while (0)
#define VM4BAR() do { FENCE(); asm volatile("s_waitcnt vmcnt(4)" ::: "memory"); \
                      __builtin_amdgcn_s_barrier(); FENCE(); } while (0)

__device__ __forceinline__ void stage_op(const unsigned short* g, int row0, int k0,
                                         char* ldsOp, int wid, int lane) {
  const int sl = lane ^ ((lane >> 4) & 1) ^ (((lane >> 5) & 1) << 1);
#pragma unroll
  for (int h = 0; h < 2; ++h)
#pragma unroll
    for (int i = 0; i < 2; ++i) {
      const int c = wid * 2 + i;
      const unsigned short* src =
          g + (size_t)(row0 + h * 128 + (c >> 1) * 16 + (sl >> 2)) * 2048 +
          (unsigned)(k0 + (c & 1) * 32 + (sl & 3) * 8);
      __builtin_amdgcn_global_load_lds(
          (__attribute__((address_space(1))) void*)src,
          (__attribute__((address_space(3))) void*)(ldsOp + h * 16384 + c * 1024),
          16, 0, 0);
    }
}

template <int N, bool EPI, bool NFAST>
__global__ void __launch_bounds__(512, 2)
gemm256(const unsigned short* __restrict__ A, const unsigned short* __restrict__ B,
        float* __restrict__ C, const float* __restrict__ resid,
        const float* __restrict__ gam) {
  constexpr int NT = 2048 / 64;         // 32 K-tiles
  constexpr int MT = MTOT / 256;        // 96
  constexpr int NXT = N / 256;
  constexpr int NWG = MT * NXT;         // %8==0 at both call sites
  constexpr int CPX = NWG / 8;
  __shared__ char lds[131072];

  const int bid = blockIdx.x;
  const int wg = (bid & 7) * CPX + (bid >> 3);   // XCD swizzle
  const int bx = NFAST ? (wg % NXT) : (wg / MT);
  const int by = NFAST ? (wg / NXT) : (wg % MT);
  const int m0 = by * 256, n0 = bx * 256;

  const int t = threadIdx.x;
  const int lane = t & 63;
  const int wid = t >> 6;
  const int wr = wid >> 2, wc = wid & 3;
  const int laneOff = (lane & 15) * 64 + (lane >> 4) * 16;
  const int swzOff = laneOff ^ (((laneOff >> 9) & 1) << 5) ^ (((laneOff >> 8) & 1) << 4);
  const int aBase = wr * 16384 + swzOff;
  const int bBase = 32768 + (wc >> 1) * 16384 + (wc & 1) * 8192 + swzOff;

  f32x4 acc[8][4] = {};

#define WRAPT(TT) ((TT) >= NT ? (TT) - NT : (TT))
#define STAGE_A(TT) stage_op(A, m0, WRAPT(TT) * 64, lds + ((TT) & 1) * 65536, wid, lane)
#define STAGE_B(TT) stage_op(B, n0, WRAPT(TT) * 64, lds + ((TT) & 1) * 65536 + 32768, wid, lane)

  // prologue: identical ledger to rounds 4-9
  STAGE_A(0);
  STAGE_B(0);
  STAGE_B(1);
  VM4BAR();

  for (int tau = 0; tau < NT; ++tau) {
    char* bufc = lds + (tau & 1) * 65536;
    STAGE_A(tau + 1);                     // other buffer: no conflict with tau reads
    // ---- reads k0 + burst k0 ----
    f16x8 Af[8], Bf[4];
#pragma unroll
    for (int m = 0; m < 4; ++m) {
      Af[m]     = *reinterpret_cast<const f16x8*>(bufc + aBase + (m * 2) * 1024);
      Af[4 + m] = *reinterpret_cast<const f16x8*>(bufc + aBase + 8192 + (m * 2) * 1024);
    }
#pragma unroll
    for (int n = 0; n < 4; ++n)
      Bf[n] = *reinterpret_cast<const f16x8*>(bufc + bBase + (n * 2) * 1024);
    __builtin_amdgcn_s_setprio(1);
#pragma unroll
    for (int m = 0; m < 8; ++m)
#pragma unroll
      for (int n = 0; n < 4; ++n)
        acc[m][n] = __builtin_amdgcn_mfma_f32_16x16x32_f16(Af[m], Bf[n], acc[m][n], 0, 0, 0);
    __builtin_amdgcn_s_setprio(0);
    // ---- reads k1 ----
    f16x8 Ag[8], Bg[4];
#pragma unroll
    for (int m = 0; m < 4; ++m) {
      Ag[m]     = *reinterpret_cast<const f16x8*>(bufc + aBase + (m * 2 + 1) * 1024);
      Ag[4 + m] = *reinterpret_cast<const f16x8*>(bufc + aBase + 8192 + (m * 2 + 1) * 1024);
    }
#pragma unroll
    for (int n = 0; n < 4; ++n)
      Bg[n] = *reinterpret_cast<const f16x8*>(bufc + bBase + (n * 2 + 1) * 1024);
    BAR();            // ROUND-11 FIX: all waves' buf-tau reads issued before overwrite
    STAGE_B(tau + 2); // overwrites buf tau B-region (parity tau) -- now safe
    VM4BAR();         // 12 -> 4: drains {A,B}(tau+1); keeps B(tau+2)
    // ---- burst k1 ----
    __builtin_amdgcn_s_setprio(1);
#pragma unroll
    for (int m = 0; m < 8; ++m)
#pragma unroll
      for (int n = 0; n < 4; ++n)
        acc[m][n] = __builtin_amdgcn_mfma_f32_16x16x32_f16(Ag[m], Bg[n], acc[m][n], 0, 0, 0);
    __builtin_amdgcn_s_setprio(0);
    BAR();            // waves' k1 reads consumed before next tile's STAGE_A overwrite
  }

#undef STAGE_A
#undef STAGE_B
#undef WRAPT

  // epilogue: C/D layout col = lane&15, row = (lane>>4)*4 + j
  const float g = EPI ? gam[0] : 0.f;
#pragma unroll
  for (int m = 0; m < 8; ++m)
#pragma unroll
    for (int n = 0; n < 4; ++n)
#pragma unroll
      for (int j = 0; j < 4; ++j) {
        const int r = m0 + wr * 128 + m * 16 + (lane >> 4) * 4 + j;
        const int c = n0 + wc * 64 + n * 16 + (lane & 15);
        const size_t idx = (size_t)r * (size_t)N + (size_t)c;
        float v = acc[m][n][j];
        if (EPI) v = g * v + resid[idx];
        C[idx] = v;
      }
}

// ---------------- per-batch: energy -> softmax -> attn out + y = attn@x ----------------
__global__ void __launch_bounds__(256)
attn_fuse(const float* __restrict__ QK,          // [MTOT, 512] cols 0..255=q, 256..511=k
          const unsigned short* __restrict__ xh, // [MTOT, 2048] fp16
          float* __restrict__ attn_out,          // [NB, 36]
          unsigned short* __restrict__ y)        // [MTOT, 2048] fp16
{
  __shared__ float qk[NS * 512];
  __shared__ float eng[36];
  __shared__ float att[36];
  const int b = blockIdx.x;
  const int t = threadIdx.x;
  {
    const f32x4* src = reinterpret_cast<const f32x4*>(QK + (size_t)b * (NS * 512));
    f32x4* dst = reinterpret_cast<f32x4*>(qk);
    for (int i = t; i < (NS * 512) / 4; i += 256) dst[i] = src[i];
  }
  __syncthreads();
  if (t < 144) {
    const int s = t / 24;
    const int rem = t - s * 24;
    const int u = rem >> 2;
    const int sub = rem & 3;
    const float* qr = qk + s * 512;
    const float* kr = qk + u * 512 + 256;
    float sum = 0.f;
    const int d0 = sub * 64;
#pragma unroll 4
    for (int d = 0; d < 64; ++d) sum += qr[d0 + d] * kr[d0 + d];
    sum += __shfl_xor(sum, 1);
    sum += __shfl_xor(sum, 2);
    if (sub == 0) eng[s * 6 + u] = sum;
  }
  __syncthreads();
  if (t < 6) {
    float e[6];
#pragma unroll
    for (int u = 0; u < 6; ++u) e[u] = eng[t * 6 + u];
    float mx = e[0];
#pragma unroll
    for (int u = 1; u < 6; ++u) mx = fmaxf(mx, e[u]);
    float p[6];
    float sm = 0.f;
#pragma unroll
    for (int u = 0; u < 6; ++u) { p[u] = expf(e[u] - mx); sm += p[u]; }
    const float inv = 1.0f / sm;
#pragma unroll
    for (int u = 0; u < 6; ++u) {
      const float a = p[u] * inv;
      att[t * 6 + u] = a;
      attn_out[(size_t)b * 36 + t * 6 + u] = a;
    }
  }
  __syncthreads();
  const unsigned short* xb = xh + (size_t)b * (NS * NC);
  unsigned short* yb = y + (size_t)b * (NS * NC);
  const int c0 = t * 8;
  f32x4 xv[12];
#pragma unroll
  for (int u = 0; u < 6; ++u) {
    u16x8 v = *reinterpret_cast<const u16x8*>(xb + u * NC + c0);
#pragma unroll
    for (int j = 0; j < 4; ++j) {
      xv[2 * u][j] = h2f(v[j]);
      xv[2 * u + 1][j] = h2f(v[4 + j]);
    }
  }
#pragma unroll
  for (int s = 0; s < 6; ++s) {
    f32x4 a0 = 0.f, a1 = 0.f;
#pragma unroll
    for (int u = 0; u < 6; ++u) {
      const float w = att[s * 6 + u];
      a0 += w * xv[2 * u];
      a1 += w * xv[2 * u + 1];
    }
    u16x8 o;
#pragma unroll
    for (int j = 0; j < 4; ++j) { o[j] = f2h_bits(a0[j]); o[4 + j] = f2h_bits(a1[j]); }
    *reinterpret_cast<u16x8*>(yb + s * NC + c0) = o;
  }
}

extern "C" void kernel_launch(void* const* d_in, const int* in_sizes, int n_in,
                              void* d_out, int out_size, void* d_ws, size_t ws_size,
                              hipStream_t stream) {
  (void)in_sizes; (void)n_in; (void)out_size; (void)ws_size;
  const float* x   = (const float*)d_in[0];
  const float* Wq  = (const float*)d_in[1];
  const float* Wk  = (const float*)d_in[2];
  const float* Wv  = (const float*)d_in[3];
  const float* gam = (const float*)d_in[4];
  float* out = (float*)d_out;
  float* attn_out = out + (size_t)MTOT * NC;

  char* ws = (char*)d_ws;
  unsigned short* xh  = (unsigned short*)(ws);                    // 100663296 B
  unsigned short* yb  = (unsigned short*)(ws + 100663296ull);     // 100663296 B (y)
  unsigned short* wqk = (unsigned short*)(ws + 201326592ull);     // 2097152 B
  unsigned short* wvh = (unsigned short*)(ws + 203423744ull);     // 8388608 B
  float*          qkb = (float*)(ws + 211812352ull);              // 50331648 B

  prep_all<<<2048, 256, 0, stream>>>(x, Wq, Wk, Wv, xh, wqk, wvh);

  // QK = x @ [Wq;Wk]^T, single-pass fp16
  gemm256<512, false, false><<<192, 512, 0, stream>>>(
      xh, wqk, qkb, nullptr, nullptr);

  // energies + softmax + attention output + y = attn @ x
  attn_fuse<<<NB, 256, 0, stream>>>(qkb, xh, attn_out, yb);

  // out = gamma * (y @ Wv^T) + x    (n-fast block order for y L2 reuse)
  gemm256<2048, true, true><<<768, 512, 0, stream>>>(
      yb, wvh, out, x, gam);
}